// Round 4
// baseline (747.008 us; speedup 1.0000x reference)
//
#include <hip/hip_runtime.h>
#include <math.h>
#include <stdint.h>

// HashEmbedder, round 6: 16B-ALIGNED pair-cell compact tables.
//
// Post-mortem r5: dur identical to r4 to 0.1% -> compiler had already merged
// the adjacent loads in r4; both rounds ran 16B loads at 8B alignment and
// compact stayed ~190 us. Hypothesis: 8B-aligned 16B gathers are split into
// two requests (TA/TCP), so 4 req/point was never achieved.
// Fix: pair cells are now explicit 16B-ALIGNED float4s.
//   Levels 0-6 (dup):      cell(i,j,k) = {v(k), v(k+1)}   D^3*16B <= 4.6 MB
//   Level 7   (half-pair): cell(i,j,m) = {v(2m), v(2m+1)} 4.41 MB (dup = 8.8
//                          would blow L2); odd-k rows take 2 adjacent-cell
//                          loads, second mostly L1-hit.
// One variable changed vs r5: hashed phase, assemble, order all unchanged.

#define NLEVELS 16
#define HASH_MASK 0x7FFFFu
#define TABLE_ENTRIES 524288  // 2^19 float2 entries per level

struct ResTable { float r[NLEVELS]; };
// dim = D = res+2; off = offset into compact buffer in 16B cells.
struct CompactMeta { int dim[8]; int off[8]; };

// ---------------------------------------------------------------- hashed path
__device__ __forceinline__ float2 gather_one_level(
    const float* __restrict__ x, const float2* __restrict__ tbl,
    float bmin0, float bmin1, float bmin2,
    float bmax0, float bmax1, float bmax2,
    float res, int point)
{
    const float* xp = x + (size_t)point * 3;
    float x0 = xp[0], x1 = xp[1], x2 = xp[2];

    float xc0 = fminf(fmaxf(x0, bmin0), bmax0);
    float xc1 = fminf(fmaxf(x1, bmin1), bmax1);
    float xc2 = fminf(fmaxf(x2, bmin2), bmax2);

    float g0 = (bmax0 - bmin0) / res;
    float g1 = (bmax1 - bmin1) / res;
    float g2 = (bmax2 - bmin2) / res;

    float f0 = floorf((xc0 - bmin0) / g0);
    float f1 = floorf((xc1 - bmin1) / g1);
    float f2 = floorf((xc2 - bmin2) / g2);
    int b0 = (int)f0, b1 = (int)f1, b2 = (int)f2;

    float vmin0 = f0 * g0 + bmin0;
    float vmin1 = f1 * g1 + bmin1;
    float vmin2 = f2 * g2 + bmin2;
    float wx = (x0 - vmin0) / g0;
    float wy = (x1 - vmin1) / g1;
    float wz = (x2 - vmin2) / g2;

    uint32_t hx0 = (uint32_t)b0;
    uint32_t hx1 = (uint32_t)(b0 + 1);
    uint32_t hy0 = (uint32_t)b1 * 2654435761u;
    uint32_t hy1 = (uint32_t)(b1 + 1) * 2654435761u;
    uint32_t hz0 = (uint32_t)b2 * 805459861u;
    uint32_t hz1 = (uint32_t)(b2 + 1) * 805459861u;

    float2 v0 = tbl[(hx0 ^ hy0 ^ hz0) & HASH_MASK];
    float2 v1 = tbl[(hx0 ^ hy0 ^ hz1) & HASH_MASK];
    float2 v2 = tbl[(hx0 ^ hy1 ^ hz0) & HASH_MASK];
    float2 v3 = tbl[(hx0 ^ hy1 ^ hz1) & HASH_MASK];
    float2 v4 = tbl[(hx1 ^ hy0 ^ hz0) & HASH_MASK];
    float2 v5 = tbl[(hx1 ^ hy0 ^ hz1) & HASH_MASK];
    float2 v6 = tbl[(hx1 ^ hy1 ^ hz0) & HASH_MASK];
    float2 v7 = tbl[(hx1 ^ hy1 ^ hz1) & HASH_MASK];

    float omx = 1.0f - wx, omy = 1.0f - wy, omz = 1.0f - wz;

    float c00_0 = v0.x * omx + v4.x * wx;
    float c00_1 = v0.y * omx + v4.y * wx;
    float c01_0 = v1.x * omx + v5.x * wx;
    float c01_1 = v1.y * omx + v5.y * wx;
    float c10_0 = v2.x * omx + v6.x * wx;
    float c10_1 = v2.y * omx + v6.y * wx;
    float c11_0 = v3.x * omx + v7.x * wx;
    float c11_1 = v3.y * omx + v7.y * wx;

    float c0_0 = c00_0 * omy + c10_0 * wy;
    float c0_1 = c00_1 * omy + c10_1 * wy;
    float c1_0 = c01_0 * omy + c11_0 * wy;
    float c1_1 = c01_1 * omy + c11_1 * wy;

    float2 o;
    o.x = c0_0 * omz + c1_0 * wz;
    o.y = c0_1 * omz + c1_1 * wz;
    return o;
}

// Hashed levels: level = blockIdx&7 + base rides round-robin block->XCD
// dispatch so each XCD's gather set is ONE 4 MB table -> L2-resident.
__global__ __launch_bounds__(256) void gather_level_kernel(
    const float* __restrict__ x,
    const float* __restrict__ emb,
    const float* __restrict__ bbox,
    float2* __restrict__ tmp,   // [NLEVELS][n_points]
    int n_points, int level_base, ResTable rt)
{
    int level = (blockIdx.x & 7) + level_base;
    int point = (blockIdx.x >> 3) * 256 + threadIdx.x;
    if (point >= n_points) return;

    float bmin0 = bbox[0], bmin1 = bbox[1], bmin2 = bbox[2];
    float bmax0 = bbox[3], bmax1 = bbox[4], bmax2 = bbox[5];

    const float2* tbl = (const float2*)emb + (size_t)level * TABLE_ENTRIES;
    float2 o = gather_one_level(x, tbl, bmin0, bmin1, bmin2,
                                bmax0, bmax1, bmax2, rt.r[level], point);
    tmp[(size_t)level * n_points + point] = o;
}

// ---------------------------------------------------------------- compact path
// Build the aligned pair-cell tables.
//  l<7 : id -> (i,j,k), cell = {ref(i,j,k), ref(i,j,k+1)}
//  l==7: id -> (i,j,m), cell = {ref(i,j,2m), ref(i,j,2m+1)}
__global__ __launch_bounds__(256) void build_compact_kernel(
    const float* __restrict__ emb,
    float4* __restrict__ compact,
    CompactMeta cm, int total)
{
    int id = blockIdx.x * 256 + threadIdx.x;
    if (id >= total) return;

    int l = 0;
#pragma unroll
    for (int t = 1; t < 8; ++t)
        if (id >= cm.off[t]) l = t;
    int local = id - cm.off[l];
    int D = cm.dim[l];

    int i, j, k0, k1;
    if (l < 7) {
        int k = local % D;
        int t2 = local / D;
        j = t2 % D; i = t2 / D;
        k0 = k; k1 = k + 1;
    } else {
        int Dm = (D + 1) >> 1;
        int m = local % Dm;
        int t2 = local / Dm;
        j = t2 % D; i = t2 / D;
        k0 = 2 * m; k1 = 2 * m + 1;
    }

    uint32_t hij = (uint32_t)i ^ ((uint32_t)j * 2654435761u);
    uint32_t h0 = (hij ^ ((uint32_t)k0 * 805459861u)) & HASH_MASK;
    uint32_t h1 = (hij ^ ((uint32_t)k1 * 805459861u)) & HASH_MASK;
    const float2* tbl = (const float2*)emb + (size_t)l * TABLE_ENTRIES;
    float2 a = tbl[h0];
    float2 b = tbl[h1];
    compact[id] = make_float4(a.x, a.y, b.x, b.y);
}

// Coarse levels 0-7: XCD-affine (level=blockIdx&7). Levels 0-6: 4 aligned
// 16B loads/point (unsplittable). Level 7: 8 loads of which even-parity rows
// duplicate an address (L1 hit) -> ~4.5 L2 req/point.
__global__ __launch_bounds__(256) void gather_compact_kernel(
    const float* __restrict__ x,
    const float4* __restrict__ compact,
    const float* __restrict__ bbox,
    float2* __restrict__ tmp,
    int n_points, CompactMeta cm, ResTable rt)
{
    int level = blockIdx.x & 7;
    int point = (blockIdx.x >> 3) * 256 + threadIdx.x;
    if (point >= n_points) return;

    float bmin0 = bbox[0], bmin1 = bbox[1], bmin2 = bbox[2];
    float bmax0 = bbox[3], bmax1 = bbox[4], bmax2 = bbox[5];
    float res = rt.r[level];

    const float* xp = x + (size_t)point * 3;
    float x0 = xp[0], x1 = xp[1], x2 = xp[2];

    float xc0 = fminf(fmaxf(x0, bmin0), bmax0);
    float xc1 = fminf(fmaxf(x1, bmin1), bmax1);
    float xc2 = fminf(fmaxf(x2, bmin2), bmax2);

    float g0 = (bmax0 - bmin0) / res;
    float g1 = (bmax1 - bmin1) / res;
    float g2 = (bmax2 - bmin2) / res;

    float f0 = floorf((xc0 - bmin0) / g0);
    float f1 = floorf((xc1 - bmin1) / g1);
    float f2 = floorf((xc2 - bmin2) / g2);
    int b0 = (int)f0, b1 = (int)f1, b2 = (int)f2;

    float vmin0 = f0 * g0 + bmin0;
    float vmin1 = f1 * g1 + bmin1;
    float vmin2 = f2 * g2 + bmin2;
    float wx = (x0 - vmin0) / g0;
    float wy = (x1 - vmin1) / g1;
    float wz = (x2 - vmin2) / g2;

    int D = cm.dim[level];
    const float4* tb = compact + cm.off[level];

    // Rows (i,j),(i,j+1),(i+1,j),(i+1,j+1); each row yields lo=v(k0), hi=v(k1).
    float2 v0, v1, v2, v3, v4, v5, v6, v7;
    if (level < 7) {
        int c = (b0 * D + b1) * D + b2;
        int dj = D, di = D * D;
        float4 q00 = tb[c];
        float4 q01 = tb[c + dj];
        float4 q10 = tb[c + di];
        float4 q11 = tb[c + di + dj];
        v0 = make_float2(q00.x, q00.y);  v1 = make_float2(q00.z, q00.w);
        v2 = make_float2(q01.x, q01.y);  v3 = make_float2(q01.z, q01.w);
        v4 = make_float2(q10.x, q10.y);  v5 = make_float2(q10.z, q10.w);
        v6 = make_float2(q11.x, q11.y);  v7 = make_float2(q11.z, q11.w);
    } else {
        int Dm = (D + 1) >> 1;
        int m0 = b2 >> 1;
        int m1 = (b2 + 1) >> 1;
        bool odd = (b2 & 1) != 0;
        int r00 = (b0 * D + b1) * Dm;
        int r01 = r00 + Dm;
        int r10 = r00 + D * Dm;
        int r11 = r10 + Dm;

        float4 a00 = tb[r00 + m0], e00 = tb[r00 + m1];
        float4 a01 = tb[r01 + m0], e01 = tb[r01 + m1];
        float4 a10 = tb[r10 + m0], e10 = tb[r10 + m1];
        float4 a11 = tb[r11 + m0], e11 = tb[r11 + m1];

        v0 = odd ? make_float2(a00.z, a00.w) : make_float2(a00.x, a00.y);
        v1 = odd ? make_float2(e00.x, e00.y) : make_float2(a00.z, a00.w);
        v2 = odd ? make_float2(a01.z, a01.w) : make_float2(a01.x, a01.y);
        v3 = odd ? make_float2(e01.x, e01.y) : make_float2(a01.z, a01.w);
        v4 = odd ? make_float2(a10.z, a10.w) : make_float2(a10.x, a10.y);
        v5 = odd ? make_float2(e10.x, e10.y) : make_float2(a10.z, a10.w);
        v6 = odd ? make_float2(a11.z, a11.w) : make_float2(a11.x, a11.y);
        v7 = odd ? make_float2(e11.x, e11.y) : make_float2(a11.z, a11.w);
    }

    float omx = 1.0f - wx, omy = 1.0f - wy, omz = 1.0f - wz;

    float c00_0 = v0.x * omx + v4.x * wx;
    float c00_1 = v0.y * omx + v4.y * wx;
    float c01_0 = v1.x * omx + v5.x * wx;
    float c01_1 = v1.y * omx + v5.y * wx;
    float c10_0 = v2.x * omx + v6.x * wx;
    float c10_1 = v2.y * omx + v6.y * wx;
    float c11_0 = v3.x * omx + v7.x * wx;
    float c11_1 = v3.y * omx + v7.y * wx;

    float c0_0 = c00_0 * omy + c10_0 * wy;
    float c0_1 = c00_1 * omy + c10_1 * wy;
    float c1_0 = c01_0 * omy + c11_0 * wy;
    float c1_1 = c01_1 * omy + c11_1 * wy;

    float2 o;
    o.x = c0_0 * omz + c1_0 * wz;
    o.y = c0_1 * omz + c1_1 * wz;
    tmp[(size_t)level * n_points + point] = o;
}

// ---------------------------------------------------------------- assemble
// LDS transpose: coalesced level-major reads -> padded LDS [256][33] ->
// contiguous float4 stores (1 KB/wave). Bank-conflict-free both phases.
__global__ __launch_bounds__(256) void assemble_lds_kernel(
    const float* __restrict__ x,
    const float2* __restrict__ tmp,
    const float* __restrict__ bbox,
    float* __restrict__ out,
    float* __restrict__ mask,
    int n_points)
{
    __shared__ float lds[256 * 33];

    const int tid = threadIdx.x;
    const int p0 = blockIdx.x * 256;
    const int p = p0 + tid;

    if (p < n_points) {
#pragma unroll
        for (int l = 0; l < NLEVELS; ++l) {
            float2 v = tmp[(size_t)l * n_points + p];
            lds[tid * 33 + 2 * l]     = v.x;
            lds[tid * 33 + 2 * l + 1] = v.y;
        }
        float bmin0 = bbox[0], bmin1 = bbox[1], bmin2 = bbox[2];
        float bmax0 = bbox[3], bmax1 = bbox[4], bmax2 = bbox[5];
        const float* xp = x + (size_t)p * 3;
        float x0 = xp[0], x1 = xp[1], x2 = xp[2];
        bool keep = (x0 >= bmin0) & (x0 <= bmax0) &
                    (x1 >= bmin1) & (x1 <= bmax1) &
                    (x2 >= bmin2) & (x2 <= bmax2);
        mask[p] = keep ? 1.0f : 0.0f;
    }

    __syncthreads();

    int nblk = n_points - p0;
    if (nblk > 256) nblk = 256;
    const int nfloat4 = nblk * 8;
    float4* dst = (float4*)(out + (size_t)p0 * 32);
#pragma unroll
    for (int j = 0; j < 8; ++j) {
        int v = j * 256 + tid;
        if (v < nfloat4) {
            int q = v >> 3;
            int k = (v & 7) << 2;
            const float* s = &lds[q * 33 + k];
            dst[v] = make_float4(s[0], s[1], s[2], s[3]);
        }
    }
}

// ---------------------------------------------------------------- fallback
__global__ __launch_bounds__(256) void hash_embed_direct_kernel(
    const float* __restrict__ x,
    const float* __restrict__ emb,
    const float* __restrict__ bbox,
    float* __restrict__ out,
    float* __restrict__ mask,
    int n_points, ResTable rt)
{
    int tid = blockIdx.x * 256 + threadIdx.x;
    int point = tid >> 4;
    int level = tid & 15;
    if (point >= n_points) return;

    float bmin0 = bbox[0], bmin1 = bbox[1], bmin2 = bbox[2];
    float bmax0 = bbox[3], bmax1 = bbox[4], bmax2 = bbox[5];

    if (level == 0) {
        const float* xp = x + (size_t)point * 3;
        float x0 = xp[0], x1 = xp[1], x2 = xp[2];
        bool keep = (x0 >= bmin0) & (x0 <= bmax0) &
                    (x1 >= bmin1) & (x1 <= bmax1) &
                    (x2 >= bmin2) & (x2 <= bmax2);
        mask[point] = keep ? 1.0f : 0.0f;
    }

    const float2* tbl = (const float2*)emb + (size_t)level * TABLE_ENTRIES;
    float2 o = gather_one_level(x, tbl, bmin0, bmin1, bmin2,
                                bmax0, bmax1, bmax2, rt.r[level], point);
    *(float2*)(out + (size_t)point * 32 + level * 2) = o;
}

// ---------------------------------------------------------------- launch
extern "C" void kernel_launch(void* const* d_in, const int* in_sizes, int n_in,
                              void* d_out, int out_size, void* d_ws, size_t ws_size,
                              hipStream_t stream) {
    const float* x    = (const float*)d_in[0];
    const float* emb  = (const float*)d_in[1];
    const float* bbox = (const float*)d_in[2];
    int n_points = in_sizes[0] / 3;

    float* out  = (float*)d_out;
    float* mask = out + (size_t)n_points * 32;

    // Host-side double libm matches numpy's resolution floor (levels
    // 3/6/9/12/15 are ulp-close to exact powers of two).
    ResTable rt;
    double b = exp((log(512.0) - log(16.0)) / 15.0);
    for (int l = 0; l < NLEVELS; ++l)
        rt.r[l] = (float)floor(16.0 * pow(b, (double)l));

    // Pair-cell geometry: D = res+2 covers corner = res+1 at the clamp
    // boundary. Levels 0-6 duplicated (D^3 cells); level 7 half-pair
    // (D*D*ceil(D/2) cells). All cells 16B.
    CompactMeta cm;
    int total_cells = 0;
    for (int l = 0; l < 8; ++l) {
        int D = (int)rt.r[l] + 2;
        cm.dim[l] = D;
        cm.off[l] = total_cells;
        int cells = (l < 7) ? D * D * D : D * D * ((D + 1) >> 1);
        total_cells += cells;
    }
    size_t tmp_bytes = (size_t)n_points * NLEVELS * sizeof(float2);
    size_t compact_bytes = (size_t)total_cells * sizeof(float4);

    int chunks = (n_points + 255) / 256;

    if (ws_size >= tmp_bytes + compact_bytes) {
        float2* tmp = (float2*)d_ws;
        float4* compact = (float4*)((char*)d_ws + tmp_bytes);

        int pre_blocks = (total_cells + 255) / 256;
        hipLaunchKernelGGL(build_compact_kernel, dim3(pre_blocks), dim3(256),
                           0, stream, emb, compact, cm, total_cells);

        dim3 grid(chunks * 8);
        // Hashed fine levels 8-15: one table per XCD, L2-resident.
        hipLaunchKernelGGL(gather_level_kernel, grid, dim3(256), 0, stream,
                           x, emb, bbox, tmp, n_points, 8, rt);
        // Compact coarse levels 0-7: aligned pair-cell loads.
        hipLaunchKernelGGL(gather_compact_kernel, grid, dim3(256), 0, stream,
                           x, compact, bbox, tmp, n_points, cm, rt);

        hipLaunchKernelGGL(assemble_lds_kernel, dim3(chunks), dim3(256), 0,
                           stream, x, tmp, bbox, out, mask, n_points);
    } else if (ws_size >= tmp_bytes) {
        float2* tmp = (float2*)d_ws;
        dim3 grid(chunks * 8);
        hipLaunchKernelGGL(gather_level_kernel, grid, dim3(256), 0, stream,
                           x, emb, bbox, tmp, n_points, 0, rt);
        hipLaunchKernelGGL(gather_level_kernel, grid, dim3(256), 0, stream,
                           x, emb, bbox, tmp, n_points, 8, rt);
        hipLaunchKernelGGL(assemble_lds_kernel, dim3(chunks), dim3(256), 0,
                           stream, x, tmp, bbox, out, mask, n_points);
    } else {
        long long total = (long long)n_points * NLEVELS;
        int blocks = (int)((total + 255) / 256);
        hipLaunchKernelGGL(hash_embed_direct_kernel, dim3(blocks), dim3(256), 0,
                           stream, x, emb, bbox, out, mask, n_points, rt);
    }
}

// Round 5
// 594.372 us; speedup vs baseline: 1.2568x; 1.2568x over previous
//
#include <hip/hip_runtime.h>
#include <math.h>
#include <stdint.h>

// HashEmbedder, round 7: balanced three-kernel pipeline.
//
// Post-mortem r6: level-per-XCD for COARSE levels = straggler disaster
// (occupancy 82->40%, dispatch runs at slowest level's pace) and dup tables
// for levels 6/7 (4.4-4.6 MB) blew the 4 MB L2 (FETCH 113 MB, thrash).
//
// New structure, balanced by construction:
//  - levels 8-15: proven hashed XCD-affine phase (218 us, 15.3 req/cyc/XCD
//    = structural floor for hash-random gathers).
//  - levels 6,7: hashed, PARITY-split (level = 6 + blockIdx&1): 4 XCDs per
//    level, per-XCD table 4 MB L2-resident, per-XCD load 2M req -> ~55 us.
//  - levels 0-5: even-pair 16B-cell compact tables, TOTAL 2.33 MB ->
//    co-resident in every XCD's L2; gathered point-major INSIDE the
//    assemble kernel (fused_tail). No affinity needed, no stragglers, no
//    staging traffic for these 6 levels. tmp shrinks 128 -> 80 MB.

#define NLEVELS 16
#define NFINE 10            // levels 6..15 staged in tmp
#define HASH_MASK 0x7FFFFu
#define TABLE_ENTRIES 524288  // 2^19 float2 entries per level

struct ResTable { float r[NLEVELS]; };
// Even-pair tables for levels 0-5: cell(i,j,m) = {v(i,j,2m), v(i,j,2m+1)},
// dim = D = res+2, Dm = ceil(D/2), off in 16B cells.
struct PairMeta { int dim[6]; int off[6]; };

// ---------------------------------------------------------------- hashed path
__device__ __forceinline__ float2 gather_one_level(
    const float* __restrict__ x, const float2* __restrict__ tbl,
    float bmin0, float bmin1, float bmin2,
    float bmax0, float bmax1, float bmax2,
    float res, int point)
{
    const float* xp = x + (size_t)point * 3;
    float x0 = xp[0], x1 = xp[1], x2 = xp[2];

    float xc0 = fminf(fmaxf(x0, bmin0), bmax0);
    float xc1 = fminf(fmaxf(x1, bmin1), bmax1);
    float xc2 = fminf(fmaxf(x2, bmin2), bmax2);

    float g0 = (bmax0 - bmin0) / res;
    float g1 = (bmax1 - bmin1) / res;
    float g2 = (bmax2 - bmin2) / res;

    float f0 = floorf((xc0 - bmin0) / g0);
    float f1 = floorf((xc1 - bmin1) / g1);
    float f2 = floorf((xc2 - bmin2) / g2);
    int b0 = (int)f0, b1 = (int)f1, b2 = (int)f2;

    float vmin0 = f0 * g0 + bmin0;
    float vmin1 = f1 * g1 + bmin1;
    float vmin2 = f2 * g2 + bmin2;
    float wx = (x0 - vmin0) / g0;
    float wy = (x1 - vmin1) / g1;
    float wz = (x2 - vmin2) / g2;

    uint32_t hx0 = (uint32_t)b0;
    uint32_t hx1 = (uint32_t)(b0 + 1);
    uint32_t hy0 = (uint32_t)b1 * 2654435761u;
    uint32_t hy1 = (uint32_t)(b1 + 1) * 2654435761u;
    uint32_t hz0 = (uint32_t)b2 * 805459861u;
    uint32_t hz1 = (uint32_t)(b2 + 1) * 805459861u;

    float2 v0 = tbl[(hx0 ^ hy0 ^ hz0) & HASH_MASK];
    float2 v1 = tbl[(hx0 ^ hy0 ^ hz1) & HASH_MASK];
    float2 v2 = tbl[(hx0 ^ hy1 ^ hz0) & HASH_MASK];
    float2 v3 = tbl[(hx0 ^ hy1 ^ hz1) & HASH_MASK];
    float2 v4 = tbl[(hx1 ^ hy0 ^ hz0) & HASH_MASK];
    float2 v5 = tbl[(hx1 ^ hy0 ^ hz1) & HASH_MASK];
    float2 v6 = tbl[(hx1 ^ hy1 ^ hz0) & HASH_MASK];
    float2 v7 = tbl[(hx1 ^ hy1 ^ hz1) & HASH_MASK];

    float omx = 1.0f - wx, omy = 1.0f - wy, omz = 1.0f - wz;

    float c00_0 = v0.x * omx + v4.x * wx;
    float c00_1 = v0.y * omx + v4.y * wx;
    float c01_0 = v1.x * omx + v5.x * wx;
    float c01_1 = v1.y * omx + v5.y * wx;
    float c10_0 = v2.x * omx + v6.x * wx;
    float c10_1 = v2.y * omx + v6.y * wx;
    float c11_0 = v3.x * omx + v7.x * wx;
    float c11_1 = v3.y * omx + v7.y * wx;

    float c0_0 = c00_0 * omy + c10_0 * wy;
    float c0_1 = c00_1 * omy + c10_1 * wy;
    float c1_0 = c01_0 * omy + c11_0 * wy;
    float c1_1 = c01_1 * omy + c11_1 * wy;

    float2 o;
    o.x = c0_0 * omz + c1_0 * wz;
    o.y = c0_1 * omz + c1_1 * wz;
    return o;
}

// 8 hashed levels, one per XCD slot (level = blockIdx&7 + base). Stores at
// tmp index (level - tmp_lo).
__global__ __launch_bounds__(256) void gather_hash8_kernel(
    const float* __restrict__ x,
    const float* __restrict__ emb,
    const float* __restrict__ bbox,
    float2* __restrict__ tmp,
    int n_points, int level_base, int tmp_lo, ResTable rt)
{
    int level = (blockIdx.x & 7) + level_base;
    int point = (blockIdx.x >> 3) * 256 + threadIdx.x;
    if (point >= n_points) return;

    float bmin0 = bbox[0], bmin1 = bbox[1], bmin2 = bbox[2];
    float bmax0 = bbox[3], bmax1 = bbox[4], bmax2 = bbox[5];

    const float2* tbl = (const float2*)emb + (size_t)level * TABLE_ENTRIES;
    float2 o = gather_one_level(x, tbl, bmin0, bmin1, bmin2,
                                bmax0, bmax1, bmax2, rt.r[level], point);
    tmp[(size_t)(level - tmp_lo) * n_points + point] = o;
}

// Levels 6,7 parity-split: 4 XCDs hold level 6's table, 4 hold level 7's.
__global__ __launch_bounds__(256) void gather_hash2_kernel(
    const float* __restrict__ x,
    const float* __restrict__ emb,
    const float* __restrict__ bbox,
    float2* __restrict__ tmp,
    int n_points, ResTable rt)
{
    int level = 6 + (blockIdx.x & 1);
    int point = (blockIdx.x >> 1) * 256 + threadIdx.x;
    if (point >= n_points) return;

    float bmin0 = bbox[0], bmin1 = bbox[1], bmin2 = bbox[2];
    float bmax0 = bbox[3], bmax1 = bbox[4], bmax2 = bbox[5];

    const float2* tbl = (const float2*)emb + (size_t)level * TABLE_ENTRIES;
    float2 o = gather_one_level(x, tbl, bmin0, bmin1, bmin2,
                                bmax0, bmax1, bmax2, rt.r[level], point);
    tmp[(size_t)(level - 6) * n_points + point] = o;
}

// ---------------------------------------------------------------- pair tables
// Build even-pair cells for levels 0-5. ~145K cells -> ~3 us.
__global__ __launch_bounds__(256) void build_pair_kernel(
    const float* __restrict__ emb,
    float4* __restrict__ pair,
    PairMeta pm, int total)
{
    int id = blockIdx.x * 256 + threadIdx.x;
    if (id >= total) return;

    int l = 0;
#pragma unroll
    for (int t = 1; t < 6; ++t)
        if (id >= pm.off[t]) l = t;
    int local = id - pm.off[l];
    int D = pm.dim[l];
    int Dm = (D + 1) >> 1;

    int m = local % Dm;
    int t2 = local / Dm;
    int j = t2 % D;
    int i = t2 / D;
    int k0 = 2 * m, k1 = 2 * m + 1;

    uint32_t hij = (uint32_t)i ^ ((uint32_t)j * 2654435761u);
    uint32_t h0 = (hij ^ ((uint32_t)k0 * 805459861u)) & HASH_MASK;
    uint32_t h1 = (hij ^ ((uint32_t)k1 * 805459861u)) & HASH_MASK;
    const float2* tbl = (const float2*)emb + (size_t)l * TABLE_ENTRIES;
    float2 a = tbl[h0];
    float2 b = tbl[h1];
    pair[id] = make_float4(a.x, a.y, b.x, b.y);
}

// ---------------------------------------------------------------- fused tail
// Point-major: gather levels 0-5 from the 2.33 MB pair tables (L2-resident
// on every XCD), read levels 6-15 from tmp (coalesced), LDS-transpose,
// coalesced float4 output + mask.
__global__ __launch_bounds__(256) void fused_tail_kernel(
    const float* __restrict__ x,
    const float4* __restrict__ pair,
    const float2* __restrict__ tmp,   // [NFINE][n_points]
    const float* __restrict__ bbox,
    float* __restrict__ out,
    float* __restrict__ mask,
    int n_points, PairMeta pm, ResTable rt)
{
    __shared__ float lds[256 * 33];

    const int tid = threadIdx.x;
    const int p0 = blockIdx.x * 256;
    const int p = p0 + tid;

    if (p < n_points) {
        float bmin0 = bbox[0], bmin1 = bbox[1], bmin2 = bbox[2];
        float bmax0 = bbox[3], bmax1 = bbox[4], bmax2 = bbox[5];

        const float* xp = x + (size_t)p * 3;
        float x0 = xp[0], x1 = xp[1], x2 = xp[2];
        bool keep = (x0 >= bmin0) & (x0 <= bmax0) &
                    (x1 >= bmin1) & (x1 <= bmax1) &
                    (x2 >= bmin2) & (x2 <= bmax2);
        mask[p] = keep ? 1.0f : 0.0f;

        float xc0 = fminf(fmaxf(x0, bmin0), bmax0);
        float xc1 = fminf(fmaxf(x1, bmin1), bmax1);
        float xc2 = fminf(fmaxf(x2, bmin2), bmax2);

#pragma unroll
        for (int l = 0; l < 6; ++l) {
            float res = rt.r[l];
            float g0 = (bmax0 - bmin0) / res;
            float g1 = (bmax1 - bmin1) / res;
            float g2 = (bmax2 - bmin2) / res;

            float f0 = floorf((xc0 - bmin0) / g0);
            float f1 = floorf((xc1 - bmin1) / g1);
            float f2 = floorf((xc2 - bmin2) / g2);
            int b0 = (int)f0, b1 = (int)f1, b2 = (int)f2;

            float vmin0 = f0 * g0 + bmin0;
            float vmin1 = f1 * g1 + bmin1;
            float vmin2 = f2 * g2 + bmin2;
            float wx = (x0 - vmin0) / g0;
            float wy = (x1 - vmin1) / g1;
            float wz = (x2 - vmin2) / g2;

            int D = pm.dim[l];
            int Dm = (D + 1) >> 1;
            const float4* tb = pair + pm.off[l];

            int m0 = b2 >> 1;
            int r00 = (b0 * D + b1) * Dm;
            int r01 = r00 + Dm;
            int r10 = r00 + D * Dm;
            int r11 = r10 + Dm;

            float4 a00 = tb[r00 + m0];
            float4 a01 = tb[r01 + m0];
            float4 a10 = tb[r10 + m0];
            float4 a11 = tb[r11 + m0];

            float2 v0, v1, v2, v3, v4, v5, v6, v7;
            if (b2 & 1) {
                // odd: v(b2) = cell(m0).hi, v(b2+1) = cell(m0+1).lo
                int m1 = m0 + 1;
                float4 e00 = tb[r00 + m1];
                float4 e01 = tb[r01 + m1];
                float4 e10 = tb[r10 + m1];
                float4 e11 = tb[r11 + m1];
                v0 = make_float2(a00.z, a00.w); v1 = make_float2(e00.x, e00.y);
                v2 = make_float2(a01.z, a01.w); v3 = make_float2(e01.x, e01.y);
                v4 = make_float2(a10.z, a10.w); v5 = make_float2(e10.x, e10.y);
                v6 = make_float2(a11.z, a11.w); v7 = make_float2(e11.x, e11.y);
            } else {
                v0 = make_float2(a00.x, a00.y); v1 = make_float2(a00.z, a00.w);
                v2 = make_float2(a01.x, a01.y); v3 = make_float2(a01.z, a01.w);
                v4 = make_float2(a10.x, a10.y); v5 = make_float2(a10.z, a10.w);
                v6 = make_float2(a11.x, a11.y); v7 = make_float2(a11.z, a11.w);
            }

            float omx = 1.0f - wx, omy = 1.0f - wy, omz = 1.0f - wz;

            float c00_0 = v0.x * omx + v4.x * wx;
            float c00_1 = v0.y * omx + v4.y * wx;
            float c01_0 = v1.x * omx + v5.x * wx;
            float c01_1 = v1.y * omx + v5.y * wx;
            float c10_0 = v2.x * omx + v6.x * wx;
            float c10_1 = v2.y * omx + v6.y * wx;
            float c11_0 = v3.x * omx + v7.x * wx;
            float c11_1 = v3.y * omx + v7.y * wx;

            float c0_0 = c00_0 * omy + c10_0 * wy;
            float c0_1 = c00_1 * omy + c10_1 * wy;
            float c1_0 = c01_0 * omy + c11_0 * wy;
            float c1_1 = c01_1 * omy + c11_1 * wy;

            lds[tid * 33 + 2 * l]     = c0_0 * omz + c1_0 * wz;
            lds[tid * 33 + 2 * l + 1] = c0_1 * omz + c1_1 * wz;
        }

#pragma unroll
        for (int l = 0; l < NFINE; ++l) {
            float2 v = tmp[(size_t)l * n_points + p];
            lds[tid * 33 + 12 + 2 * l]     = v.x;
            lds[tid * 33 + 12 + 2 * l + 1] = v.y;
        }
    }

    __syncthreads();

    int nblk = n_points - p0;
    if (nblk > 256) nblk = 256;
    const int nfloat4 = nblk * 8;
    float4* dst = (float4*)(out + (size_t)p0 * 32);
#pragma unroll
    for (int j = 0; j < 8; ++j) {
        int v = j * 256 + tid;
        if (v < nfloat4) {
            int q = v >> 3;
            int k = (v & 7) << 2;
            const float* s = &lds[q * 33 + k];
            dst[v] = make_float4(s[0], s[1], s[2], s[3]);
        }
    }
}

// ---------------------------------------------------------------- mid tier
// 16-level tmp + LDS-transposed assemble (r4 structure) when pair buffer
// doesn't fit.
__global__ __launch_bounds__(256) void assemble_lds_kernel(
    const float* __restrict__ x,
    const float2* __restrict__ tmp,
    const float* __restrict__ bbox,
    float* __restrict__ out,
    float* __restrict__ mask,
    int n_points)
{
    __shared__ float lds[256 * 33];

    const int tid = threadIdx.x;
    const int p0 = blockIdx.x * 256;
    const int p = p0 + tid;

    if (p < n_points) {
#pragma unroll
        for (int l = 0; l < NLEVELS; ++l) {
            float2 v = tmp[(size_t)l * n_points + p];
            lds[tid * 33 + 2 * l]     = v.x;
            lds[tid * 33 + 2 * l + 1] = v.y;
        }
        float bmin0 = bbox[0], bmin1 = bbox[1], bmin2 = bbox[2];
        float bmax0 = bbox[3], bmax1 = bbox[4], bmax2 = bbox[5];
        const float* xp = x + (size_t)p * 3;
        float x0 = xp[0], x1 = xp[1], x2 = xp[2];
        bool keep = (x0 >= bmin0) & (x0 <= bmax0) &
                    (x1 >= bmin1) & (x1 <= bmax1) &
                    (x2 >= bmin2) & (x2 <= bmax2);
        mask[p] = keep ? 1.0f : 0.0f;
    }

    __syncthreads();

    int nblk = n_points - p0;
    if (nblk > 256) nblk = 256;
    const int nfloat4 = nblk * 8;
    float4* dst = (float4*)(out + (size_t)p0 * 32);
#pragma unroll
    for (int j = 0; j < 8; ++j) {
        int v = j * 256 + tid;
        if (v < nfloat4) {
            int q = v >> 3;
            int k = (v & 7) << 2;
            const float* s = &lds[q * 33 + k];
            dst[v] = make_float4(s[0], s[1], s[2], s[3]);
        }
    }
}

// ---------------------------------------------------------------- fallback
__global__ __launch_bounds__(256) void hash_embed_direct_kernel(
    const float* __restrict__ x,
    const float* __restrict__ emb,
    const float* __restrict__ bbox,
    float* __restrict__ out,
    float* __restrict__ mask,
    int n_points, ResTable rt)
{
    int tid = blockIdx.x * 256 + threadIdx.x;
    int point = tid >> 4;
    int level = tid & 15;
    if (point >= n_points) return;

    float bmin0 = bbox[0], bmin1 = bbox[1], bmin2 = bbox[2];
    float bmax0 = bbox[3], bmax1 = bbox[4], bmax2 = bbox[5];

    if (level == 0) {
        const float* xp = x + (size_t)point * 3;
        float x0 = xp[0], x1 = xp[1], x2 = xp[2];
        bool keep = (x0 >= bmin0) & (x0 <= bmax0) &
                    (x1 >= bmin1) & (x1 <= bmax1) &
                    (x2 >= bmin2) & (x2 <= bmax2);
        mask[point] = keep ? 1.0f : 0.0f;
    }

    const float2* tbl = (const float2*)emb + (size_t)level * TABLE_ENTRIES;
    float2 o = gather_one_level(x, tbl, bmin0, bmin1, bmin2,
                                bmax0, bmax1, bmax2, rt.r[level], point);
    *(float2*)(out + (size_t)point * 32 + level * 2) = o;
}

// ---------------------------------------------------------------- launch
extern "C" void kernel_launch(void* const* d_in, const int* in_sizes, int n_in,
                              void* d_out, int out_size, void* d_ws, size_t ws_size,
                              hipStream_t stream) {
    const float* x    = (const float*)d_in[0];
    const float* emb  = (const float*)d_in[1];
    const float* bbox = (const float*)d_in[2];
    int n_points = in_sizes[0] / 3;

    float* out  = (float*)d_out;
    float* mask = out + (size_t)n_points * 32;

    // Host-side double libm matches numpy's resolution floor (levels
    // 3/6/9/12/15 are ulp-close to exact powers of two).
    ResTable rt;
    double b = exp((log(512.0) - log(16.0)) / 15.0);
    for (int l = 0; l < NLEVELS; ++l)
        rt.r[l] = (float)floor(16.0 * pow(b, (double)l));

    // Even-pair geometry for levels 0-5: D = res+2 (corners reach res+1 at
    // the clamp boundary), Dm = ceil(D/2). Total ~145K cells = 2.33 MB.
    PairMeta pm;
    int total_cells = 0;
    for (int l = 0; l < 6; ++l) {
        int D = (int)rt.r[l] + 2;
        pm.dim[l] = D;
        pm.off[l] = total_cells;
        total_cells += D * D * ((D + 1) >> 1);
    }

    size_t tmp10_bytes = (size_t)n_points * NFINE * sizeof(float2);
    size_t tmp16_bytes = (size_t)n_points * NLEVELS * sizeof(float2);
    size_t pair_bytes  = (size_t)total_cells * sizeof(float4);

    int chunks = (n_points + 255) / 256;

    if (ws_size >= tmp10_bytes + pair_bytes) {
        float2* tmp  = (float2*)d_ws;
        float4* pair = (float4*)((char*)d_ws + tmp10_bytes);

        int pre_blocks = (total_cells + 255) / 256;
        hipLaunchKernelGGL(build_pair_kernel, dim3(pre_blocks), dim3(256),
                           0, stream, emb, pair, pm, total_cells);

        // Levels 8-15: one 4 MB table per XCD (proven 218 us).
        hipLaunchKernelGGL(gather_hash8_kernel, dim3(chunks * 8), dim3(256),
                           0, stream, x, emb, bbox, tmp, n_points, 8, 6, rt);
        // Levels 6,7: parity-split across XCDs (~55 us).
        hipLaunchKernelGGL(gather_hash2_kernel, dim3(chunks * 2), dim3(256),
                           0, stream, x, emb, bbox, tmp, n_points, rt);
        // Levels 0-5 gather (L2-resident pair tables) + transpose + output.
        hipLaunchKernelGGL(fused_tail_kernel, dim3(chunks), dim3(256),
                           0, stream, x, pair, tmp, bbox, out, mask,
                           n_points, pm, rt);
    } else if (ws_size >= tmp16_bytes) {
        float2* tmp = (float2*)d_ws;
        dim3 grid(chunks * 8);
        hipLaunchKernelGGL(gather_hash8_kernel, grid, dim3(256), 0, stream,
                           x, emb, bbox, tmp, n_points, 0, 0, rt);
        hipLaunchKernelGGL(gather_hash8_kernel, grid, dim3(256), 0, stream,
                           x, emb, bbox, tmp, n_points, 8, 0, rt);
        hipLaunchKernelGGL(assemble_lds_kernel, dim3(chunks), dim3(256), 0,
                           stream, x, tmp, bbox, out, mask, n_points);
    } else {
        long long total = (long long)n_points * NLEVELS;
        int blocks = (int)((total + 255) / 256);
        hipLaunchKernelGGL(hash_embed_direct_kernel, dim3(blocks), dim3(256), 0,
                           stream, x, emb, bbox, out, mask, n_points, rt);
    }
}